// Round 7
// baseline (1164.616 us; speedup 1.0000x reference)
//
#include <hip/hip_runtime.h>
#include <hip/hip_bf16.h>
#include <hip/hip_fp16.h>
#include <cmath>

typedef __hip_bfloat16 bf16;

__device__ __forceinline__ float b2f(bf16 x) { return __bfloat162float(x); }
__device__ __forceinline__ float bfu(unsigned short s) {
    unsigned int t = ((unsigned int)s) << 16; float f;
    __builtin_memcpy(&f, &t, 4); return f;
}
__device__ __forceinline__ float ldf(const void* p, long long i, int f32) {
    return f32 ? ((const float*)p)[i] : b2f(((const bf16*)p)[i]);
}
__device__ __forceinline__ float ldA(const float* p, long long i) { return p[i]; }
__device__ __forceinline__ float ldA(const bf16* p, long long i)  { return b2f(p[i]); }
__device__ __forceinline__ void  stA(float* p, long long i, float v) { p[i] = v; }
__device__ __forceinline__ void  stA(bf16* p, long long i, float v)  { p[i] = __float2bfloat16(v); }

// ---- vector helpers (callers guarantee alignment) ----
__device__ __forceinline__ void ld2(const float* p, float o[2]) {
    float2 u = *(const float2*)p; o[0]=u.x; o[1]=u.y;
}
__device__ __forceinline__ void ld2(const bf16* p, float o[2]) {
    unsigned int u = *(const unsigned int*)p;
    o[0]=bfu(u&0xffff); o[1]=bfu((unsigned short)(u>>16));
}

// X 2-px raw-load conversion: 2 VALU ops (shift keeps low bf16, mask keeps high)
__device__ __forceinline__ void xcvt2(unsigned int u, float o[2]) {
    unsigned int lo = u << 16;
    unsigned int hi = u & 0xffff0000u;
    __builtin_memcpy(&o[0], &lo, 4);
    __builtin_memcpy(&o[1], &hi, 4);
}
__device__ __forceinline__ void xcvt2(float2 u, float o[2]) { o[0] = u.x; o[1] = u.y; }

#define RR 8     // endmembers
#define G2CH 8   // chunks (of 128 px) per k_g2 wave
#define G2PX (G2CH * 128)

// flags: [0]=X f32? [1]=M0 [2]=A0 [3]=Wa [4]=lambd [5]=L [6]=L2 [7]=p
//        [8]=alpha [9]=tau [10]=H [11]=W
// sc: [0]=Lk [1]=alpha [2]=pk [3]=lmbda(prox) [4]=inv8 [5]=L2k

// ---------------------------------------------------------------------------
// Wave-parallel probe.
__global__ void k_probe(
    const void* X, long long nX, const void* M0, long long nM0,
    const void* A0, long long nA0, const void* Wa, long long nWa,
    const void* lamb, const void* Larr, const void* L2arr,
    const void* parr, const void* alarr, const void* tauarr,
    const void* Hp, const void* Wp, int N, int* flags)
{
    int lane = threadIdx.x;           // 64 threads, 1 block
    const void* rnd[4] = {X, M0, A0, Wa};
    long long cnt[4] = {nX, nM0, nA0, nWa};
    for (int t = 0; t < 4; t++) {
        const bf16* pb = (const bf16*)rnd[t];
        long long stride = cnt[t] / 128; if (stride < 1) stride = 1;
        bool ok = true;
#pragma unroll
        for (int q = 0; q < 2; q++) {
            long long idx = (long long)(lane + q * 64) * stride;
            if (idx < cnt[t]) {
                float v = b2f(pb[idx]);
                ok = ok && (v > -100.f && v < 100.f);
            }
        }
        unsigned long long m = __ballot(ok);
        if (lane == 0) flags[t] = (m == 0xFFFFFFFFFFFFFFFFULL) ? 0 : 1;
    }
    if (lane != 0) return;
    const void* cst[6] = {lamb, Larr, L2arr, parr, alarr, tauarr};
    for (int t = 0; t < 6; t++) {
        const unsigned short* u = (const unsigned short*)cst[t];
        flags[4 + t] = (u[0] == u[1]) ? 0 : 1;
    }
    int dims[2];
    const void* dp[2] = {Hp, Wp};
    for (int t = 0; t < 2; t++) {
        int d = -1;
        int c = ((const int*)dp[t])[0];
        if (c >= 1 && c <= N && N % c == 0) d = c;
        if (d < 0) {
            float f = ((const float*)dp[t])[0];
            int cf = (int)(f + 0.5f);
            if (f >= 1.f && f <= (float)N && cf >= 1 && N % cf == 0) d = cf;
        }
        if (d < 0) {
            float g = b2f(((const bf16*)dp[t])[0]);
            int cg = (int)(g + 0.5f);
            if (g >= 1.f && g <= (float)N && cg >= 1 && N % cg == 0) d = cg;
        }
        if (d < 0) { d = 1; while ((long long)d * d < N) d <<= 1; }
        dims[t] = d;
    }
    if ((long long)dims[0] * dims[1] != N) dims[1] = N / dims[0];
    flags[10] = dims[0];
    flags[11] = dims[1];
}

// ---------------------------------------------------------------------------
template <typename T>
__global__ void __launch_bounds__(256) k_init(
    const void* __restrict__ A0, const void* __restrict__ M0,
    T* __restrict__ A1, float* __restrict__ Mbuf,
    int N, int MRtot, const int* __restrict__ flags)
{
    int n = blockIdx.x * blockDim.x + threadIdx.x;
    int fA = flags[2], fM = flags[1];
    if (n < N) {
#pragma unroll
        for (int r = 0; r < RR; r++)
            stA(A1, (long long)r * N + n, ldf(A0, (long long)n * RR + r, fA));
    }
    if (n < MRtot) Mbuf[n] = ldf(M0, n, fM);
}

// ---------------------------------------------------------------------------
// Per-iteration setup. If do_updM: apply the PREVIOUS iteration's M update,
// then zero G1/G2, load Wf, constants, WM = Wf^T M (4-way band-parallel).
__global__ void k_pre(
    const void* __restrict__ Wa, const void* __restrict__ lambd,
    const void* __restrict__ Larr, const void* __restrict__ L2arr,
    const void* __restrict__ parr, const void* __restrict__ alarr,
    const void* __restrict__ tauarr, int k, int do_updM,
    float* __restrict__ Mbuf,
    float* __restrict__ Wf, float* __restrict__ WM,
    float* __restrict__ cst_tau, float* __restrict__ cst_plam,
    float* __restrict__ sc, float* __restrict__ G2, float* __restrict__ G1,
    int g2len, int bands, const int* __restrict__ flags)
{
    extern __shared__ float smem[];
    float* Ms  = smem;                       // bands*RR
    float* G1s = smem + bands * RR;          // 64
    float* sm2 = G1s + 64;                   // 256 scratch
    int tid = threadIdx.x;
    int fW = flags[3];
    if (do_updM) {
        float L2k = sc[5];  // iter k-1's L2
        for (int i = tid; i < bands * RR; i += blockDim.x) Ms[i] = Mbuf[i];
        for (int i = tid; i < 64; i += blockDim.x) G1s[i] = G1[i];
        __syncthreads();
        for (int i = tid; i < bands * RR; i += blockDim.x) {
            int r = i & 7;
            int b8 = i & ~7;
            float g = -G2[i];
#pragma unroll
            for (int r2 = 0; r2 < RR; r2++) g = fmaf(Ms[b8 + r2], G1s[r2 * RR + r], g);
            Mbuf[i] = fmaxf(Ms[i] - L2k * g, 0.f);
        }
        __syncthreads();
    }
    for (int i = tid; i < bands * RR; i += blockDim.x)
        Wf[i] = ldf(Wa, (long long)k * bands * RR + i, fW);
    for (int i = tid; i < g2len; i += blockDim.x) G2[i] = 0.f;
    if (tid < 64) G1[tid] = 0.f;
    if (tid == 0) {
        float Lk  = ldf(Larr,  k, flags[5]);
        float al  = ldf(alarr, k, flags[8]);
        float pk  = ldf(parr,  k, flags[7]);
        float ta  = ldf(tauarr,k, flags[9]);
        float L2k = ldf(L2arr, k, flags[6]);
        float lmb = (al != 0.f) ? 2.f * ta / al : 0.f;
        sc[0] = Lk; sc[1] = al; sc[2] = pk; sc[3] = lmb;
        sc[4] = (lmb > 1e-30f) ? 1.f / (8.f * lmb) : 0.f;
        sc[5] = L2k;
    }
    if (tid < RR) {
        float pk  = ldf(parr, k, flags[7]);
        float lam = ldf(lambd, (long long)k * RR + tid, flags[4]);
        float e1 = 1.f / (2.f - pk);
        float e2 = (pk - 1.f) / (2.f - pk);
        float t = powf(2.f * (1.f - pk) * lam, e1)
                + pk * lam * powf(2.f * lam * (1.f - pk), e2);
        cst_tau[tid]  = t;
        cst_plam[tid] = pk * lam;
    }
    __syncthreads();
    {
        int pr = tid >> 2, qt = tid & 3;     // tid < 256
        int r = pr >> 3, r2 = pr & 7;
        float s = 0.f;
        for (int b = qt; b < bands; b += 4) s += Wf[b * RR + r] * Mbuf[b * RR + r2];
        sm2[tid] = s;
    }
    __syncthreads();
    if (tid < RR * RR)
        WM[tid] = sm2[tid * 4] + sm2[tid * 4 + 1] + sm2[tid * 4 + 2] + sm2[tid * 4 + 3];
}

// ---------------------------------------------------------------------------
// update_A with 2-way band split: 512-thread block covers 256 px; half h
// accumulates wx over bands [h*bands/2, ...) with an 8-deep register ring
// (compile-time indices). h=1 stages partials to LDS (8 KB), h=0 combines.
// NO min-waves launch bound (round-5 lesson: forcing occupancy -> spill);
// depth-8 ring keeps live state <=64 VGPR (m69: the 8-waves/SIMD step).
template <typename T>
__global__ void __launch_bounds__(512) k_updA(
    const void* __restrict__ X, const T* __restrict__ A1,
    const float* __restrict__ Wf, const float* __restrict__ WM,
    const float* __restrict__ cst_tau, const float* __restrict__ cst_plam,
    const float* __restrict__ sc, T* __restrict__ A2,
    long long N, int bands, const int* __restrict__ flags, int first)
{
    __shared__ float lwx[RR * 256];
    int tid = threadIdx.x;
    int h = tid >> 8, t = tid & 255;
    long long n = (long long)blockIdx.x * 256 + t;
    int valid = (n < N);
    long long nn = valid ? n : (N - 1);
    int xf = flags[0];
    const bf16*  Xb = (const bf16*)X;
    const float* Xf = (const float*)X;

    int h1 = bands >> 1;
    int hb0 = h ? h1 : 0;
    int hb1 = h ? bands : h1;

    float wx[RR];
#pragma unroll
    for (int r = 0; r < RR; r++) wx[r] = 0.f;

    float xq[8];
#pragma unroll
    for (int i = 0; i < 8; i++)
        xq[i] = (hb0 + i < hb1) ? (xf ? Xf[(long long)(hb0 + i) * N + nn]
                                      : b2f(Xb[(long long)(hb0 + i) * N + nn])) : 0.f;
    int b0 = hb0;
    for (; b0 + 8 <= hb1; b0 += 8) {
#pragma unroll
        for (int bi = 0; bi < 8; bi++) {
            float xc = xq[bi];
            int bn = b0 + 8 + bi;
            xq[bi] = (bn < hb1) ? (xf ? Xf[(long long)bn * N + nn]
                                      : b2f(Xb[(long long)bn * N + nn])) : 0.f;
            const float* wrow = Wf + (b0 + bi) * RR;
#pragma unroll
            for (int r = 0; r < RR; r++) wx[r] = fmaf(wrow[r], xc, wx[r]);
        }
    }
#pragma unroll
    for (int bi = 0; bi < 8; bi++) {
        if (b0 + bi < hb1) {
            float xc = xq[bi];
            const float* wrow = Wf + (b0 + bi) * RR;
#pragma unroll
            for (int r = 0; r < RR; r++) wx[r] = fmaf(wrow[r], xc, wx[r]);
        }
    }

    if (h == 1) {
#pragma unroll
        for (int r = 0; r < RR; r++) lwx[r * 256 + t] = wx[r];
    }
    // h=0: issue A1 loads before the barrier so they overlap h=1's tail
    float a[RR];
    if (h == 0) {
#pragma unroll
        for (int r = 0; r < RR; r++) a[r] = ldA(A1, (long long)r * N + nn);
    }
    __syncthreads();
    if (h != 0 || !valid) return;

#pragma unroll
    for (int r = 0; r < RR; r++) wx[r] += lwx[r * 256 + t];

    float bv[RR];
    if (first) {
#pragma unroll
        for (int r = 0; r < RR; r++) bv[r] = a[r];
    } else {
        float sb = 0.f;
#pragma unroll
        for (int r = 0; r < RR; r++) { float rl = fmaxf(a[r], 0.f); bv[r] = rl; sb += rl; }
        float invb = 1.f / (sb + 1e-4f);
#pragma unroll
        for (int r = 0; r < RR; r++) bv[r] *= invb;
    }

    float Lk = sc[0], al = sc[1], pk = sc[2];
    float o[RR]; float s = 0.f;
#pragma unroll
    for (int r = 0; r < RR; r++) {
        float gg = al * (a[r] - bv[r]) - wx[r];
#pragma unroll
        for (int r2 = 0; r2 < RR; r2++) gg = fmaf(WM[r * RR + r2], a[r2], gg);
        float v = a[r] - Lk * gg;
        float tt = 0.f;
        if (v > cst_tau[r]) {
            float vp = (pk == 0.5f) ? rsqrtf(v) : powf(v, pk - 1.f);
            tt = v - cst_plam[r] * vp;
        }
        tt = fminf(tt, 1.f);
        tt = fmaxf(tt, 0.f);
        o[r] = tt;
        s += tt;
    }
    float inv = 1.f / (s + 1e-4f);
#pragma unroll
    for (int r = 0; r < RR; r++) stA(A2, (long long)r * N + n, o[r] * inv);
}

// ---------------------------------------------------------------------------
// prox_TV per pixel per channel (unchanged).
template <typename T>
__global__ void __launch_bounds__(256) k_prox(
    const T* __restrict__ Ain, T* __restrict__ Aout,
    const float* __restrict__ sc, const int* __restrict__ flags, int N)
{
    int n = blockIdx.x * blockDim.x + threadIdx.x;
    if (n >= N) return;
    int H = flags[10], W = flags[11];
    int i = n / W, j = n % W;
    float lmb  = sc[3];
    float inv8 = sc[4];
#pragma unroll
    for (int r = 0; r < RR; r++) {
        const T* img = Ain + (long long)r * N;
        float c   = ldA(img, n);
        float dwn = (i < H - 1) ? ldA(img, n + W) : c;
        float rgt = (j < W - 1) ? ldA(img, n + 1) : c;
        float rr0 = (c - dwn) * inv8;
        float ss0 = (c - rgt) * inv8;
        float w0 = fmaxf(1.f, sqrtf(rr0 * rr0 + ss0 * ss0 + 1e-8f));
        float rn00 = rr0 / w0, sn00 = ss0 / w0;
        float rnU = 0.f;
        if (i > 0) {
            float cu = ldA(img, n - W);
            float ru = (j < W - 1) ? ldA(img, n - W + 1) : cu;
            float rru = (cu - c) * inv8;
            float ssu = (cu - ru) * inv8;
            float wu = fmaxf(1.f, sqrtf(rru * rru + ssu * ssu + 1e-8f));
            rnU = rru / wu;
        }
        float snL = 0.f;
        if (j > 0) {
            float cl = ldA(img, n - 1);
            float dl = (i < H - 1) ? ldA(img, n + W - 1) : cl;
            float rrl = (cl - dl) * inv8;
            float ssl = (cl - c) * inv8;
            float wl2 = fmaxf(1.f, sqrtf(rrl * rrl + ssl * ssl + 1e-8f));
            snL = ssl / wl2;
        }
        float div = rn00 - rnU + sn00 - snL;
        stA(Aout, (long long)r * N + n, c - lmb * div);
    }
}

// ---------------------------------------------------------------------------
// Butterfly stages with compile-time indexing (round-2 lesson).
template <int H>
__device__ __forceinline__ void bstep(float* v, int lane) {
    int up = (lane & H) != 0;
#pragma unroll
    for (int i = 0; i < H; i++) {
        float give = up ? v[i] : v[i + H];
        float keep = up ? v[i + H] : v[i];
        v[i] = keep + __shfl_xor(give, H, 64);
    }
}
// 32 columns over 64 lanes: after the xor-32 fold, lanes l and l+32 both
// hold column (l&31); bstep<16..1> finishes. Caller uses lanes < 32.
__device__ __forceinline__ float butterfly32(float v[32], int lane) {
#pragma unroll
    for (int i = 0; i < 32; i++) v[i] += __shfl_xor(v[i], 32, 64);
    bstep<16>(v, lane);
    bstep<8>(v, lane);
    bstep<4>(v, lane);
    bstep<2>(v, lane);
    bstep<1>(v, lane);
    return v[0];
}

// ---------------------------------------------------------------------------
// G2 = X A^T and G1 = A A^T, split by (4-band group, pixel-tile).
// pacc[32] (vs round-6's pacc[64]) targets <=64 VGPR = the 8-waves/SIMD
// occupancy step; per-r streaming A loads keep live state small.
// grid = (ceil(N/1024), ngroups4 + 2); slots [ngroups4, ngroups4+1] do
// G1 rows 0-3 / 4-7. One butterfly + one 32-lane atomic per wave.
template <typename T>
__global__ void __launch_bounds__(64) k_g2(
    const void* __restrict__ X, const T* __restrict__ A,
    float* __restrict__ G2, float* __restrict__ G1,
    long long N, int bands, int ngroups4, const int* __restrict__ flags)
{
    int lane = threadIdx.x;
    long long p0 = (long long)blockIdx.x * G2PX;
    int gy = blockIdx.y;
    int xf = flags[0];
    int fast = (p0 + G2PX <= N) && ((N & 1LL) == 0);

    float pacc[32];
#pragma unroll
    for (int q = 0; q < 32; q++) pacc[q] = 0.f;

    if (gy < ngroups4) {
        int b0 = gy * 4;
        if (fast) {
            long long half = N >> 1;
#pragma unroll
            for (int c = 0; c < G2CH; c++) {
                long long base = p0 + (long long)c * 128 + lane * 2;
                long long gi = base >> 1;
                float xv[4][2];
                if (!xf) {
                    const unsigned int* Xu = (const unsigned int*)X;
#pragma unroll
                    for (int bi = 0; bi < 4; bi++) {
                        int b = b0 + bi;
                        unsigned int u = (b < bands) ? Xu[(long long)b * half + gi] : 0u;
                        xcvt2(u, xv[bi]);
                    }
                } else {
                    const float2* Xf2 = (const float2*)X;
#pragma unroll
                    for (int bi = 0; bi < 4; bi++) {
                        int b = b0 + bi;
                        float2 u = (b < bands) ? Xf2[(long long)b * half + gi]
                                               : make_float2(0.f, 0.f);
                        xcvt2(u, xv[bi]);
                    }
                }
#pragma unroll
                for (int r = 0; r < RR; r++) {
                    float av[2];
                    ld2(A + (long long)r * N + base, av);
#pragma unroll
                    for (int bi = 0; bi < 4; bi++)
                        pacc[bi * 8 + r] = fmaf(xv[bi][0], av[0],
                                            fmaf(xv[bi][1], av[1], pacc[bi * 8 + r]));
                }
            }
        } else {
            for (int c = 0; c < G2CH; c++) {
                long long n0 = p0 + (long long)c * 128;
                if (n0 >= N) break;
                long long base = n0 + lane * 2;
                float xv[4][2] = {};
#pragma unroll
                for (int bi = 0; bi < 4; bi++) {
                    int b = b0 + bi;
#pragma unroll
                    for (int t = 0; t < 2; t++) {
                        long long idx = base + t;
                        if (b < bands && idx < N)
                            xv[bi][t] = ldf(X, (long long)b * N + idx, xf);
                    }
                }
#pragma unroll
                for (int r = 0; r < RR; r++) {
                    float av[2] = {0.f, 0.f};
#pragma unroll
                    for (int t = 0; t < 2; t++) {
                        long long idx = base + t;
                        if (idx < N) av[t] = ldA(A, (long long)r * N + idx);
                    }
#pragma unroll
                    for (int bi = 0; bi < 4; bi++)
                        pacc[bi * 8 + r] = fmaf(xv[bi][0], av[0],
                                            fmaf(xv[bi][1], av[1], pacc[bi * 8 + r]));
                }
            }
        }
        float s = butterfly32(pacc, lane);
        int q = lane & 31;
        int b = b0 + (q >> 3);
        if (lane < 32 && b < bands) atomicAdd(&G2[b * 8 + (q & 7)], s);
    } else {
        // G1 rows r0..r0+3 (r0 = 0 or 4)
        int r0 = (gy - ngroups4) * 4;
        if (fast) {
#pragma unroll
            for (int c = 0; c < G2CH; c++) {
                long long base = p0 + (long long)c * 128 + lane * 2;
                float xv[4][2];
#pragma unroll
                for (int bi = 0; bi < 4; bi++) ld2(A + (long long)(r0 + bi) * N + base, xv[bi]);
#pragma unroll
                for (int r = 0; r < RR; r++) {
                    float av[2];
                    ld2(A + (long long)r * N + base, av);
#pragma unroll
                    for (int bi = 0; bi < 4; bi++)
                        pacc[bi * 8 + r] = fmaf(xv[bi][0], av[0],
                                            fmaf(xv[bi][1], av[1], pacc[bi * 8 + r]));
                }
            }
        } else {
            for (int c = 0; c < G2CH; c++) {
                long long n0 = p0 + (long long)c * 128;
                if (n0 >= N) break;
                long long base = n0 + lane * 2;
                float xv[4][2] = {};
#pragma unroll
                for (int bi = 0; bi < 4; bi++)
#pragma unroll
                    for (int t = 0; t < 2; t++) {
                        long long idx = base + t;
                        if (idx < N) xv[bi][t] = ldA(A, (long long)(r0 + bi) * N + idx);
                    }
#pragma unroll
                for (int r = 0; r < RR; r++) {
                    float av[2] = {0.f, 0.f};
#pragma unroll
                    for (int t = 0; t < 2; t++) {
                        long long idx = base + t;
                        if (idx < N) av[t] = ldA(A, (long long)r * N + idx);
                    }
#pragma unroll
                    for (int bi = 0; bi < 4; bi++)
                        pacc[bi * 8 + r] = fmaf(xv[bi][0], av[0],
                                            fmaf(xv[bi][1], av[1], pacc[bi * 8 + r]));
                }
            }
        }
        float s = butterfly32(pacc, lane);
        int q = lane & 31;
        if (lane < 32) atomicAdd(&G1[(r0 + (q >> 3)) * 8 + (q & 7)], s);
    }
}

// ---------------------------------------------------------------------------
// Final M update (last iteration only; earlier ones are folded into k_pre).
__global__ void __launch_bounds__(256) k_updateM(
    float* __restrict__ Mbuf, const float* __restrict__ G1,
    const float* __restrict__ G2, const float* __restrict__ sc, int bands)
{
    extern __shared__ float smem[];
    float* Ms  = smem;
    float* G1s = smem + bands * RR;
    int tid = threadIdx.x;
    for (int i = tid; i < bands * RR; i += 256) Ms[i] = Mbuf[i];
    for (int i = tid; i < RR * RR; i += 256) G1s[i] = G1[i];
    __syncthreads();
    float L2k = sc[5];
    for (int i = tid; i < bands * RR; i += 256) {
        int b = i >> 3, r = i & 7;
        float g = -G2[i];
#pragma unroll
        for (int r2 = 0; r2 < RR; r2++) g = fmaf(Ms[b * RR + r2], G1s[r2 * RR + r], g);
        Mbuf[i] = fmaxf(Ms[i] - L2k * g, 0.f);
    }
}

// ---------------------------------------------------------------------------
template <typename T>
__global__ void __launch_bounds__(256) k_out(
    const float* __restrict__ Mbuf, const T* __restrict__ A1,
    void* __restrict__ out, int MR, int RN, const int* __restrict__ flags)
{
    int i = blockIdx.x * blockDim.x + threadIdx.x;
    if (flags[0]) {
        float* o = (float*)out;
        if (i < MR) o[i] = Mbuf[i];
        if (i < RN) o[MR + i] = ldA(A1, i);
    } else {
        bf16* o = (bf16*)out;
        if (i < MR) o[i] = __float2bfloat16(Mbuf[i]);
        if (i < RN) o[MR + i] = __float2bfloat16(ldA(A1, i));
    }
}

// ---------------------------------------------------------------------------
template <typename T>
static void run_all(const void* X, const void* M0, const void* A0, const void* Wa,
                    const void* lambd, const void* Larr, const void* L2arr,
                    const void* parr, const void* alarr, const void* tauarr,
                    T* A1, T* A2, float* Mbuf, float* Wf,
                    float* WM, float* G1, float* G2, float* cst_tau, float* cst_plam,
                    float* sc, int* flags, void* out,
                    int N, int bands, int Rr, int K, int g2len, hipStream_t stream)
{
    int nb = (N + 255) / 256;
    int ntiles = (N + G2PX - 1) / G2PX;
    int ngroups4 = (bands + 3) / 4;
    int MR = bands * Rr;
    size_t smem_pre = ((size_t)bands * Rr + 64 + 256) * sizeof(float);

    k_init<T><<<nb, 256, 0, stream>>>(A0, M0, A1, Mbuf, N, MR, flags);

    for (int k = 0; k < K; k++) {
        k_pre<<<1, 256, smem_pre, stream>>>(Wa, lambd, Larr, L2arr, parr, alarr,
                                            tauarr, k, (k > 0) ? 1 : 0, Mbuf, Wf, WM,
                                            cst_tau, cst_plam, sc, G2, G1,
                                            g2len, bands, flags);
        k_updA<T><<<nb, 512, 0, stream>>>(X, A1, Wf, WM, cst_tau, cst_plam, sc,
                                          A2, (long long)N, bands, flags,
                                          (k == 0) ? 1 : 0);
        k_prox<T><<<nb, 256, 0, stream>>>(A2, A1, sc, flags, N);
        k_g2<T><<<dim3(ntiles, ngroups4 + 2), 64, 0, stream>>>(X, A1, G2, G1,
                                                               (long long)N, bands,
                                                               ngroups4, flags);
    }
    k_updateM<<<1, 256, smem_pre, stream>>>(Mbuf, G1, G2, sc, bands);
    k_out<T><<<((size_t)N * Rr + 255) / 256, 256, 0, stream>>>(Mbuf, A1, out, MR, N * Rr, flags);
}

// ---------------------------------------------------------------------------
extern "C" void kernel_launch(void* const* d_in, const int* in_sizes, int n_in,
                              void* d_out, int out_size, void* d_ws, size_t ws_size,
                              hipStream_t stream)
{
    const void* X      = d_in[0];
    const void* M0     = d_in[1];
    const void* A0     = d_in[2];
    const void* Wa     = d_in[3];
    const void* lambd  = d_in[4];
    const void* Larr   = d_in[5];
    const void* L2arr  = d_in[6];
    const void* parr   = d_in[7];
    const void* alarr  = d_in[8];
    const void* tauarr = d_in[9];
    const void* Hp     = d_in[10];
    const void* Wp     = d_in[11];

    int K = in_sizes[5];
    long long s0 = in_sizes[0], s1 = in_sizes[1], s2 = in_sizes[2];
    int Rr = (int)llround(sqrt((double)(s1 * s2) / (double)s0));  // == 8
    int bands = (int)(s1 / Rr);
    int N = (int)(s2 / Rr);
    size_t NR = (size_t)N * Rr;
    int groups = (bands + 7) / 8;
    int g2len = groups * 64;

    // --- workspace layout: small state first, then A buffers ---
    float* wsf = (float*)d_ws;
    int*   flags    = (int*)wsf;            // 16 ints
    float* sc       = wsf + 16;             // 8
    float* Mbuf     = wsf + 24;             // bands*Rr
    float* Wf       = Mbuf + bands * Rr;    // bands*Rr
    float* WM       = Wf + bands * Rr;      // 64
    float* G1       = WM + 64;              // 64
    float* G2       = G1 + 64;              // g2len
    float* cst_tau  = G2 + g2len;           // 8
    float* cst_plam = cst_tau + 8;          // 8
    size_t smallEnd = 24 + 2 * (size_t)bands * Rr + 128 + (size_t)g2len + 16;
    size_t Aoff = (smallEnd + 1023) & ~(size_t)1023;

    size_t need32 = (Aoff + 2 * NR) * sizeof(float);   // f32 A1+A2

    k_probe<<<1, 64, 0, stream>>>(X, s0, M0, s1, A0, s2, Wa, (long long)in_sizes[3],
                                  lambd, Larr, L2arr, parr, alarr, tauarr,
                                  Hp, Wp, N, flags);

    if (ws_size >= need32) {
        float* A1 = wsf + Aoff;
        float* A2 = A1 + NR;
        run_all<float>(X, M0, A0, Wa, lambd, Larr, L2arr, parr, alarr, tauarr,
                       A1, A2, Mbuf, Wf, WM, G1, G2,
                       cst_tau, cst_plam, sc, flags, d_out,
                       N, bands, Rr, K, g2len, stream);
    } else {
        bf16* A1 = (bf16*)(wsf + Aoff);
        bf16* A2 = A1 + NR;
        run_all<bf16>(X, M0, A0, Wa, lambd, Larr, L2arr, parr, alarr, tauarr,
                      A1, A2, Mbuf, Wf, WM, G1, G2,
                      cst_tau, cst_plam, sc, flags, d_out,
                      N, bands, Rr, K, g2len, stream);
    }
}

// Round 8
// 976.227 us; speedup vs baseline: 1.1930x; 1.1930x over previous
//
#include <hip/hip_runtime.h>
#include <hip/hip_bf16.h>
#include <hip/hip_fp16.h>
#include <cmath>

typedef __hip_bfloat16 bf16;

__device__ __forceinline__ float b2f(bf16 x) { return __bfloat162float(x); }
__device__ __forceinline__ float bfu(unsigned short s) {
    unsigned int t = ((unsigned int)s) << 16; float f;
    __builtin_memcpy(&f, &t, 4); return f;
}
__device__ __forceinline__ float ldf(const void* p, long long i, int f32) {
    return f32 ? ((const float*)p)[i] : b2f(((const bf16*)p)[i]);
}
__device__ __forceinline__ float ldA(const float* p, long long i) { return p[i]; }
__device__ __forceinline__ float ldA(const bf16* p, long long i)  { return b2f(p[i]); }
__device__ __forceinline__ void  stA(float* p, long long i, float v) { p[i] = v; }
__device__ __forceinline__ void  stA(bf16* p, long long i, float v)  { p[i] = __float2bfloat16(v); }

// WtX-typed helpers (f32 tier uses float, bf16 tier uses fp16 for mantissa)
__device__ __forceinline__ float ldW(const float* p, long long i) { return p[i]; }
__device__ __forceinline__ float ldW(const __half* p, long long i) { return __half2float(p[i]); }
__device__ __forceinline__ void  stW(float* p, long long i, float v) { p[i] = v; }
__device__ __forceinline__ void  stW(__half* p, long long i, float v) { p[i] = __float2half(v); }

// ---- vector helpers (callers guarantee alignment) ----
__device__ __forceinline__ void ld2(const float* p, float o[2]) {
    float2 u = *(const float2*)p; o[0]=u.x; o[1]=u.y;
}
__device__ __forceinline__ void ld2(const bf16* p, float o[2]) {
    unsigned int u = *(const unsigned int*)p;
    o[0]=bfu(u&0xffff); o[1]=bfu((unsigned short)(u>>16));
}

// X 2-px raw-load conversion: 2 VALU ops (shift keeps low bf16, mask keeps high)
__device__ __forceinline__ void xcvt2(unsigned int u, float o[2]) {
    unsigned int lo = u << 16;
    unsigned int hi = u & 0xffff0000u;
    __builtin_memcpy(&o[0], &lo, 4);
    __builtin_memcpy(&o[1], &hi, 4);
}
__device__ __forceinline__ void xcvt2(float2 u, float o[2]) { o[0] = u.x; o[1] = u.y; }

#define RR 8     // endmembers
#define G2CH 8   // chunks (of 128 px) per k_g2 wave
#define G2PX (G2CH * 128)

// flags: [0]=X f32? [1]=M0 [2]=A0 [3]=Wa [4]=lambd [5]=L [6]=L2 [7]=p
//        [8]=alpha [9]=tau [10]=H [11]=W [12]=Wa constant across k?
// sc: [0]=Lk [1]=alpha [2]=pk [3]=lmbda(prox) [4]=inv8 [5]=L2k

// ---------------------------------------------------------------------------
// Wave-parallel probe + W_a k-invariance detection (full bitwise check).
__global__ void k_probe(
    const void* X, long long nX, const void* M0, long long nM0,
    const void* A0, long long nA0, const void* Wa, long long nWa,
    const void* lamb, const void* Larr, const void* L2arr,
    const void* parr, const void* alarr, const void* tauarr,
    const void* Hp, const void* Wp, int N, int K, int* flags)
{
    int lane = threadIdx.x;           // 64 threads, 1 block
    const void* rnd[4] = {X, M0, A0, Wa};
    long long cnt[4] = {nX, nM0, nA0, nWa};
    unsigned long long mW = ~0ULL;
    for (int t = 0; t < 4; t++) {
        const bf16* pb = (const bf16*)rnd[t];
        long long stride = cnt[t] / 128; if (stride < 1) stride = 1;
        bool ok = true;
#pragma unroll
        for (int q = 0; q < 2; q++) {
            long long idx = (long long)(lane + q * 64) * stride;
            if (idx < cnt[t]) {
                float v = b2f(pb[idx]);
                ok = ok && (v > -100.f && v < 100.f);
            }
        }
        unsigned long long m = __ballot(ok);
        if (t == 3) mW = m;
        if (lane == 0) flags[t] = (m == 0xFFFFFFFFFFFFFFFFULL) ? 0 : 1;
    }
    // --- W_a constancy across the K leading blocks (bitwise, full) ---
    {
        int fWa = (mW == 0xFFFFFFFFFFFFFFFFULL) ? 0 : 1;   // 0 = bf16, 1 = f32
        long long perk = (K > 0) ? (nWa / K) : nWa;        // elements per k
        long long nu16 = fWa ? perk * 2 : perk;            // u16 units per block
        const unsigned short* wu = (const unsigned short*)Wa;
        bool ok = true;
        for (long long i = lane; i < nu16; i += 64) {
            unsigned short v0 = wu[i];
            for (int k2 = 1; k2 < K; k2++)
                ok = ok && (wu[i + (long long)k2 * nu16] == v0);
        }
        unsigned long long m = __ballot(ok);
        if (lane == 0) flags[12] = (m == 0xFFFFFFFFFFFFFFFFULL) ? 1 : 0;
    }
    if (lane != 0) return;
    const void* cst[6] = {lamb, Larr, L2arr, parr, alarr, tauarr};
    for (int t = 0; t < 6; t++) {
        const unsigned short* u = (const unsigned short*)cst[t];
        flags[4 + t] = (u[0] == u[1]) ? 0 : 1;
    }
    int dims[2];
    const void* dp[2] = {Hp, Wp};
    for (int t = 0; t < 2; t++) {
        int d = -1;
        int c = ((const int*)dp[t])[0];
        if (c >= 1 && c <= N && N % c == 0) d = c;
        if (d < 0) {
            float f = ((const float*)dp[t])[0];
            int cf = (int)(f + 0.5f);
            if (f >= 1.f && f <= (float)N && cf >= 1 && N % cf == 0) d = cf;
        }
        if (d < 0) {
            float g = b2f(((const bf16*)dp[t])[0]);
            int cg = (int)(g + 0.5f);
            if (g >= 1.f && g <= (float)N && cg >= 1 && N % cg == 0) d = cg;
        }
        if (d < 0) { d = 1; while ((long long)d * d < N) d <<= 1; }
        dims[t] = d;
    }
    if ((long long)dims[0] * dims[1] != N) dims[1] = N / dims[0];
    flags[10] = dims[0];
    flags[11] = dims[1];
}

// ---------------------------------------------------------------------------
template <typename T>
__global__ void __launch_bounds__(256) k_init(
    const void* __restrict__ A0, const void* __restrict__ M0,
    T* __restrict__ A1, float* __restrict__ Mbuf,
    int N, int MRtot, const int* __restrict__ flags)
{
    int n = blockIdx.x * blockDim.x + threadIdx.x;
    int fA = flags[2], fM = flags[1];
    if (n < N) {
#pragma unroll
        for (int r = 0; r < RR; r++)
            stA(A1, (long long)r * N + n, ldf(A0, (long long)n * RR + r, fA));
    }
    if (n < MRtot) Mbuf[n] = ldf(M0, n, fM);
}

// ---------------------------------------------------------------------------
// Per-iteration setup. If do_updM: apply the PREVIOUS iteration's M update,
// then zero G1/G2, load Wf, constants, WM = Wf^T M (4-way band-parallel).
__global__ void k_pre(
    const void* __restrict__ Wa, const void* __restrict__ lambd,
    const void* __restrict__ Larr, const void* __restrict__ L2arr,
    const void* __restrict__ parr, const void* __restrict__ alarr,
    const void* __restrict__ tauarr, int k, int do_updM,
    float* __restrict__ Mbuf,
    float* __restrict__ Wf, float* __restrict__ WM,
    float* __restrict__ cst_tau, float* __restrict__ cst_plam,
    float* __restrict__ sc, float* __restrict__ G2, float* __restrict__ G1,
    int g2len, int bands, const int* __restrict__ flags)
{
    extern __shared__ float smem[];
    float* Ms  = smem;                       // bands*RR
    float* G1s = smem + bands * RR;          // 64
    float* sm2 = G1s + 64;                   // 256 scratch
    int tid = threadIdx.x;
    int fW = flags[3];
    if (do_updM) {
        float L2k = sc[5];  // iter k-1's L2
        for (int i = tid; i < bands * RR; i += blockDim.x) Ms[i] = Mbuf[i];
        for (int i = tid; i < 64; i += blockDim.x) G1s[i] = G1[i];
        __syncthreads();
        for (int i = tid; i < bands * RR; i += blockDim.x) {
            int r = i & 7;
            int b8 = i & ~7;
            float g = -G2[i];
#pragma unroll
            for (int r2 = 0; r2 < RR; r2++) g = fmaf(Ms[b8 + r2], G1s[r2 * RR + r], g);
            Mbuf[i] = fmaxf(Ms[i] - L2k * g, 0.f);
        }
        __syncthreads();
    }
    for (int i = tid; i < bands * RR; i += blockDim.x)
        Wf[i] = ldf(Wa, (long long)k * bands * RR + i, fW);
    for (int i = tid; i < g2len; i += blockDim.x) G2[i] = 0.f;
    if (tid < 64) G1[tid] = 0.f;
    if (tid == 0) {
        float Lk  = ldf(Larr,  k, flags[5]);
        float al  = ldf(alarr, k, flags[8]);
        float pk  = ldf(parr,  k, flags[7]);
        float ta  = ldf(tauarr,k, flags[9]);
        float L2k = ldf(L2arr, k, flags[6]);
        float lmb = (al != 0.f) ? 2.f * ta / al : 0.f;
        sc[0] = Lk; sc[1] = al; sc[2] = pk; sc[3] = lmb;
        sc[4] = (lmb > 1e-30f) ? 1.f / (8.f * lmb) : 0.f;
        sc[5] = L2k;
    }
    if (tid < RR) {
        float pk  = ldf(parr, k, flags[7]);
        float lam = ldf(lambd, (long long)k * RR + tid, flags[4]);
        float e1 = 1.f / (2.f - pk);
        float e2 = (pk - 1.f) / (2.f - pk);
        float t = powf(2.f * (1.f - pk) * lam, e1)
                + pk * lam * powf(2.f * lam * (1.f - pk), e2);
        cst_tau[tid]  = t;
        cst_plam[tid] = pk * lam;
    }
    __syncthreads();
    {
        int pr = tid >> 2, qt = tid & 3;     // tid < 256
        int r = pr >> 3, r2 = pr & 7;
        float s = 0.f;
        for (int b = qt; b < bands; b += 4) s += Wf[b * RR + r] * Mbuf[b * RR + r2];
        sm2[tid] = s;
    }
    __syncthreads();
    if (tid < RR * RR)
        WM[tid] = sm2[tid * 4] + sm2[tid * 4 + 1] + sm2[tid * 4 + 2] + sm2[tid * 4 + 3];
}

// ---------------------------------------------------------------------------
// WtX = W^T X, one pass over X, 8-deep register ring over bands (round-6
// updA's band loop verbatim -> identical FMA order -> identical f32 result).
// Runs once; early-outs if W varies across k (flags[12]==0).
template <typename TW>
__global__ void __launch_bounds__(256) k_wtx(
    const void* __restrict__ X, const float* __restrict__ Wf,
    TW* __restrict__ WtX, long long N, int bands, const int* __restrict__ flags)
{
    if (!flags[12]) return;
    long long n = (long long)blockIdx.x * 256 + threadIdx.x;
    if (n >= N) return;
    int xf = flags[0];
    const bf16*  Xb = (const bf16*)X;
    const float* Xf = (const float*)X;

    float wx[RR];
#pragma unroll
    for (int r = 0; r < RR; r++) wx[r] = 0.f;

    float xq[8];
#pragma unroll
    for (int i = 0; i < 8; i++)
        xq[i] = (i < bands) ? (xf ? Xf[(long long)i * N + n]
                                  : b2f(Xb[(long long)i * N + n])) : 0.f;
    int b0 = 0;
    for (; b0 + 8 <= bands; b0 += 8) {
#pragma unroll
        for (int bi = 0; bi < 8; bi++) {
            float xc = xq[bi];
            int bn = b0 + 8 + bi;
            xq[bi] = (bn < bands) ? (xf ? Xf[(long long)bn * N + n]
                                        : b2f(Xb[(long long)bn * N + n])) : 0.f;
            const float* wrow = Wf + (b0 + bi) * RR;
#pragma unroll
            for (int r = 0; r < RR; r++) wx[r] = fmaf(wrow[r], xc, wx[r]);
        }
    }
#pragma unroll
    for (int bi = 0; bi < 8; bi++) {
        if (b0 + bi < bands) {
            float xc = xq[bi];
            const float* wrow = Wf + (b0 + bi) * RR;
#pragma unroll
            for (int r = 0; r < RR; r++) wx[r] = fmaf(wrow[r], xc, wx[r]);
        }
    }
#pragma unroll
    for (int r = 0; r < RR; r++) stW(WtX, (long long)r * N + n, wx[r]);
}

// ---------------------------------------------------------------------------
// update_A. W-constant fast path: wx streamed from precomputed WtX (no X
// read; ~24 MB total traffic). Fallback (W varies per k): round-6 on-the-fly
// band loop with 8-deep ring. Wave-uniform branch on flags[12].
template <typename T, typename TW>
__global__ void __launch_bounds__(256) k_updA(
    const void* __restrict__ X, const T* __restrict__ A1,
    const TW* __restrict__ WtX,
    const float* __restrict__ Wf, const float* __restrict__ WM,
    const float* __restrict__ cst_tau, const float* __restrict__ cst_plam,
    const float* __restrict__ sc, T* __restrict__ A2,
    long long N, int bands, const int* __restrict__ flags, int first)
{
    long long n = (long long)blockIdx.x * 256 + threadIdx.x;
    if (n >= N) return;

    float wx[RR];
    if (flags[12]) {
#pragma unroll
        for (int r = 0; r < RR; r++) wx[r] = ldW(WtX, (long long)r * N + n);
    } else {
        int xf = flags[0];
        const bf16*  Xb = (const bf16*)X;
        const float* Xf = (const float*)X;
#pragma unroll
        for (int r = 0; r < RR; r++) wx[r] = 0.f;
        float xq[8];
#pragma unroll
        for (int i = 0; i < 8; i++)
            xq[i] = (i < bands) ? (xf ? Xf[(long long)i * N + n]
                                      : b2f(Xb[(long long)i * N + n])) : 0.f;
        int b0 = 0;
        for (; b0 + 8 <= bands; b0 += 8) {
#pragma unroll
            for (int bi = 0; bi < 8; bi++) {
                float xc = xq[bi];
                int bn = b0 + 8 + bi;
                xq[bi] = (bn < bands) ? (xf ? Xf[(long long)bn * N + n]
                                            : b2f(Xb[(long long)bn * N + n])) : 0.f;
                const float* wrow = Wf + (b0 + bi) * RR;
#pragma unroll
                for (int r = 0; r < RR; r++) wx[r] = fmaf(wrow[r], xc, wx[r]);
            }
        }
#pragma unroll
        for (int bi = 0; bi < 8; bi++) {
            if (b0 + bi < bands) {
                float xc = xq[bi];
                const float* wrow = Wf + (b0 + bi) * RR;
#pragma unroll
                for (int r = 0; r < RR; r++) wx[r] = fmaf(wrow[r], xc, wx[r]);
            }
        }
    }

    float a[RR], bv[RR];
#pragma unroll
    for (int r = 0; r < RR; r++) a[r] = ldA(A1, (long long)r * N + n);
    if (first) {
#pragma unroll
        for (int r = 0; r < RR; r++) bv[r] = a[r];
    } else {
        float sb = 0.f;
#pragma unroll
        for (int r = 0; r < RR; r++) { float rl = fmaxf(a[r], 0.f); bv[r] = rl; sb += rl; }
        float invb = 1.f / (sb + 1e-4f);
#pragma unroll
        for (int r = 0; r < RR; r++) bv[r] *= invb;
    }

    // ---- prox-gradient step ----
    float Lk = sc[0], al = sc[1], pk = sc[2];
    float o[RR]; float s = 0.f;
#pragma unroll
    for (int r = 0; r < RR; r++) {
        float gg = al * (a[r] - bv[r]) - wx[r];
#pragma unroll
        for (int r2 = 0; r2 < RR; r2++) gg = fmaf(WM[r * RR + r2], a[r2], gg);
        float v = a[r] - Lk * gg;
        float t = 0.f;
        if (v > cst_tau[r]) {
            float vp = (pk == 0.5f) ? rsqrtf(v) : powf(v, pk - 1.f);
            t = v - cst_plam[r] * vp;
        }
        t = fminf(t, 1.f);
        t = fmaxf(t, 0.f);
        o[r] = t;
        s += t;
    }
    float inv = 1.f / (s + 1e-4f);
#pragma unroll
    for (int r = 0; r < RR; r++) stA(A2, (long long)r * N + n, o[r] * inv);
}

// ---------------------------------------------------------------------------
// prox_TV per pixel per channel (unchanged).
template <typename T>
__global__ void __launch_bounds__(256) k_prox(
    const T* __restrict__ Ain, T* __restrict__ Aout,
    const float* __restrict__ sc, const int* __restrict__ flags, int N)
{
    int n = blockIdx.x * blockDim.x + threadIdx.x;
    if (n >= N) return;
    int H = flags[10], W = flags[11];
    int i = n / W, j = n % W;
    float lmb  = sc[3];
    float inv8 = sc[4];
#pragma unroll
    for (int r = 0; r < RR; r++) {
        const T* img = Ain + (long long)r * N;
        float c   = ldA(img, n);
        float dwn = (i < H - 1) ? ldA(img, n + W) : c;
        float rgt = (j < W - 1) ? ldA(img, n + 1) : c;
        float rr0 = (c - dwn) * inv8;
        float ss0 = (c - rgt) * inv8;
        float w0 = fmaxf(1.f, sqrtf(rr0 * rr0 + ss0 * ss0 + 1e-8f));
        float rn00 = rr0 / w0, sn00 = ss0 / w0;
        float rnU = 0.f;
        if (i > 0) {
            float cu = ldA(img, n - W);
            float ru = (j < W - 1) ? ldA(img, n - W + 1) : cu;
            float rru = (cu - c) * inv8;
            float ssu = (cu - ru) * inv8;
            float wu = fmaxf(1.f, sqrtf(rru * rru + ssu * ssu + 1e-8f));
            rnU = rru / wu;
        }
        float snL = 0.f;
        if (j > 0) {
            float cl = ldA(img, n - 1);
            float dl = (i < H - 1) ? ldA(img, n + W - 1) : cl;
            float rrl = (cl - dl) * inv8;
            float ssl = (cl - c) * inv8;
            float wl2 = fmaxf(1.f, sqrtf(rrl * rrl + ssl * ssl + 1e-8f));
            snL = ssl / wl2;
        }
        float div = rn00 - rnU + sn00 - snL;
        stA(Aout, (long long)r * N + n, c - lmb * div);
    }
}

// ---------------------------------------------------------------------------
// Register butterfly transpose-reduce, compile-time indexing throughout
// (round-2 lesson: runtime index into a register array -> scratch).
template <int H>
__device__ __forceinline__ void bstep(float* v, int lane) {
    int up = (lane & H) != 0;
#pragma unroll
    for (int i = 0; i < H; i++) {
        float give = up ? v[i] : v[i + H];
        float keep = up ? v[i + H] : v[i];
        v[i] = keep + __shfl_xor(give, H, 64);
    }
}
__device__ __forceinline__ float butterfly64(float v[64], int lane) {
    bstep<32>(v, lane);
    bstep<16>(v, lane);
    bstep<8>(v, lane);
    bstep<4>(v, lane);
    bstep<2>(v, lane);
    bstep<1>(v, lane);
    return v[0];
}

// ---------------------------------------------------------------------------
// G2 = X A^T and G1 = A A^T, split by (8-band group, pixel-tile). Round-6
// version verbatim (best measured). grid = (ceil(N/1024), groups+1), 1 wave.
template <typename T>
__global__ void __launch_bounds__(64) k_g2(
    const void* __restrict__ X, const T* __restrict__ A,
    float* __restrict__ G2, float* __restrict__ G1,
    long long N, int bands, int groups, const int* __restrict__ flags)
{
    int lane = threadIdx.x;
    long long p0 = (long long)blockIdx.x * G2PX;
    int gy = blockIdx.y;
    int xf = flags[0];
    int fast = (p0 + G2PX <= N) && ((N & 1LL) == 0);

    float pacc[64];
#pragma unroll
    for (int q = 0; q < 64; q++) pacc[q] = 0.f;

    if (gy < groups) {
        int b0g = gy * 8;
        if (fast) {
            long long half = N >> 1;
#pragma unroll
            for (int c = 0; c < G2CH; c++) {
                long long base = p0 + (long long)c * 128 + lane * 2;
                long long gi = base >> 1;
                float av[RR][2], xv[8][2];
#pragma unroll
                for (int r = 0; r < RR; r++) ld2(A + (long long)r * N + base, av[r]);
                if (!xf) {
                    const unsigned int* Xu = (const unsigned int*)X;
#pragma unroll
                    for (int bi = 0; bi < 8; bi++) {
                        int b = b0g + bi;
                        unsigned int u = (b < bands) ? Xu[(long long)b * half + gi] : 0u;
                        xcvt2(u, xv[bi]);
                    }
                } else {
                    const float2* Xf2 = (const float2*)X;
#pragma unroll
                    for (int bi = 0; bi < 8; bi++) {
                        int b = b0g + bi;
                        float2 u = (b < bands) ? Xf2[(long long)b * half + gi]
                                               : make_float2(0.f, 0.f);
                        xcvt2(u, xv[bi]);
                    }
                }
#pragma unroll
                for (int bi = 0; bi < 8; bi++)
#pragma unroll
                    for (int r = 0; r < RR; r++)
                        pacc[bi * 8 + r] = fmaf(xv[bi][0], av[r][0],
                                            fmaf(xv[bi][1], av[r][1], pacc[bi * 8 + r]));
            }
        } else {
            for (int c = 0; c < G2CH; c++) {
                long long n0 = p0 + (long long)c * 128;
                if (n0 >= N) break;
                long long base = n0 + lane * 2;
                float av[RR][2] = {}, xv[8][2] = {};
#pragma unroll
                for (int r = 0; r < RR; r++)
#pragma unroll
                    for (int t = 0; t < 2; t++) {
                        long long idx = base + t;
                        if (idx < N) av[r][t] = ldA(A, (long long)r * N + idx);
                    }
#pragma unroll
                for (int bi = 0; bi < 8; bi++) {
                    int b = b0g + bi;
#pragma unroll
                    for (int t = 0; t < 2; t++) {
                        long long idx = base + t;
                        if (b < bands && idx < N)
                            xv[bi][t] = ldf(X, (long long)b * N + idx, xf);
                    }
                }
#pragma unroll
                for (int bi = 0; bi < 8; bi++)
#pragma unroll
                    for (int r = 0; r < RR; r++)
                        pacc[bi * 8 + r] = fmaf(xv[bi][0], av[r][0],
                                            fmaf(xv[bi][1], av[r][1], pacc[bi * 8 + r]));
            }
        }
        float s = butterfly64(pacc, lane);
        atomicAdd(&G2[gy * 64 + lane], s);
    } else {
        // G1 = A A^T over this wave's pixels
        if (fast) {
#pragma unroll
            for (int c = 0; c < G2CH; c++) {
                long long base = p0 + (long long)c * 128 + lane * 2;
                float av[RR][2];
#pragma unroll
                for (int r = 0; r < RR; r++) ld2(A + (long long)r * N + base, av[r]);
#pragma unroll
                for (int i2 = 0; i2 < 8; i2++)
#pragma unroll
                    for (int j2 = 0; j2 < 8; j2++)
                        pacc[i2 * 8 + j2] = fmaf(av[i2][0], av[j2][0],
                                             fmaf(av[i2][1], av[j2][1], pacc[i2 * 8 + j2]));
            }
        } else {
            for (int c = 0; c < G2CH; c++) {
                long long n0 = p0 + (long long)c * 128;
                if (n0 >= N) break;
                long long base = n0 + lane * 2;
                float av[RR][2] = {};
#pragma unroll
                for (int r = 0; r < RR; r++)
#pragma unroll
                    for (int t = 0; t < 2; t++) {
                        long long idx = base + t;
                        if (idx < N) av[r][t] = ldA(A, (long long)r * N + idx);
                    }
#pragma unroll
                for (int i2 = 0; i2 < 8; i2++)
#pragma unroll
                    for (int j2 = 0; j2 < 8; j2++)
                        pacc[i2 * 8 + j2] = fmaf(av[i2][0], av[j2][0],
                                             fmaf(av[i2][1], av[j2][1], pacc[i2 * 8 + j2]));
            }
        }
        float s = butterfly64(pacc, lane);
        atomicAdd(&G1[lane], s);
    }
}

// ---------------------------------------------------------------------------
// Final M update (last iteration only; earlier ones are folded into k_pre).
__global__ void __launch_bounds__(256) k_updateM(
    float* __restrict__ Mbuf, const float* __restrict__ G1,
    const float* __restrict__ G2, const float* __restrict__ sc, int bands)
{
    extern __shared__ float smem[];
    float* Ms  = smem;
    float* G1s = smem + bands * RR;
    int tid = threadIdx.x;
    for (int i = tid; i < bands * RR; i += 256) Ms[i] = Mbuf[i];
    for (int i = tid; i < RR * RR; i += 256) G1s[i] = G1[i];
    __syncthreads();
    float L2k = sc[5];
    for (int i = tid; i < bands * RR; i += 256) {
        int b = i >> 3, r = i & 7;
        float g = -G2[i];
#pragma unroll
        for (int r2 = 0; r2 < RR; r2++) g = fmaf(Ms[b * RR + r2], G1s[r2 * RR + r], g);
        Mbuf[i] = fmaxf(Ms[i] - L2k * g, 0.f);
    }
}

// ---------------------------------------------------------------------------
template <typename T>
__global__ void __launch_bounds__(256) k_out(
    const float* __restrict__ Mbuf, const T* __restrict__ A1,
    void* __restrict__ out, int MR, int RN, const int* __restrict__ flags)
{
    int i = blockIdx.x * blockDim.x + threadIdx.x;
    if (flags[0]) {
        float* o = (float*)out;
        if (i < MR) o[i] = Mbuf[i];
        if (i < RN) o[MR + i] = ldA(A1, i);
    } else {
        bf16* o = (bf16*)out;
        if (i < MR) o[i] = __float2bfloat16(Mbuf[i]);
        if (i < RN) o[MR + i] = __float2bfloat16(ldA(A1, i));
    }
}

// ---------------------------------------------------------------------------
template <typename T, typename TW>
static void run_all(const void* X, const void* M0, const void* A0, const void* Wa,
                    const void* lambd, const void* Larr, const void* L2arr,
                    const void* parr, const void* alarr, const void* tauarr,
                    T* A1, T* A2, TW* WtX, float* Mbuf, float* Wf,
                    float* WM, float* G1, float* G2, float* cst_tau, float* cst_plam,
                    float* sc, int* flags, void* out,
                    int N, int bands, int Rr, int K, int g2len, hipStream_t stream)
{
    int nb = (N + 255) / 256;
    int ntiles = (N + G2PX - 1) / G2PX;
    int groups = (bands + 7) / 8;
    int MR = bands * Rr;
    size_t smem_pre = ((size_t)bands * Rr + 64 + 256) * sizeof(float);

    k_init<T><<<nb, 256, 0, stream>>>(A0, M0, A1, Mbuf, N, MR, flags);

    // k=0 setup, then one-time WtX pass (self-disables if W varies per k)
    k_pre<<<1, 256, smem_pre, stream>>>(Wa, lambd, Larr, L2arr, parr, alarr,
                                        tauarr, 0, 0, Mbuf, Wf, WM,
                                        cst_tau, cst_plam, sc, G2, G1,
                                        g2len, bands, flags);
    k_wtx<TW><<<nb, 256, 0, stream>>>(X, Wf, WtX, (long long)N, bands, flags);

    for (int k = 0; k < K; k++) {
        if (k > 0)
            k_pre<<<1, 256, smem_pre, stream>>>(Wa, lambd, Larr, L2arr, parr, alarr,
                                                tauarr, k, 1, Mbuf, Wf, WM,
                                                cst_tau, cst_plam, sc, G2, G1,
                                                g2len, bands, flags);
        k_updA<T, TW><<<nb, 256, 0, stream>>>(X, A1, WtX, Wf, WM, cst_tau, cst_plam,
                                              sc, A2, (long long)N, bands, flags,
                                              (k == 0) ? 1 : 0);
        k_prox<T><<<nb, 256, 0, stream>>>(A2, A1, sc, flags, N);
        k_g2<T><<<dim3(ntiles, groups + 1), 64, 0, stream>>>(X, A1, G2, G1,
                                                             (long long)N, bands,
                                                             groups, flags);
    }
    k_updateM<<<1, 256, smem_pre, stream>>>(Mbuf, G1, G2, sc, bands);
    k_out<T><<<((size_t)N * Rr + 255) / 256, 256, 0, stream>>>(Mbuf, A1, out, MR, N * Rr, flags);
}

// ---------------------------------------------------------------------------
extern "C" void kernel_launch(void* const* d_in, const int* in_sizes, int n_in,
                              void* d_out, int out_size, void* d_ws, size_t ws_size,
                              hipStream_t stream)
{
    const void* X      = d_in[0];
    const void* M0     = d_in[1];
    const void* A0     = d_in[2];
    const void* Wa     = d_in[3];
    const void* lambd  = d_in[4];
    const void* Larr   = d_in[5];
    const void* L2arr  = d_in[6];
    const void* parr   = d_in[7];
    const void* alarr  = d_in[8];
    const void* tauarr = d_in[9];
    const void* Hp     = d_in[10];
    const void* Wp     = d_in[11];

    int K = in_sizes[5];
    long long s0 = in_sizes[0], s1 = in_sizes[1], s2 = in_sizes[2];
    int Rr = (int)llround(sqrt((double)(s1 * s2) / (double)s0));  // == 8
    int bands = (int)(s1 / Rr);
    int N = (int)(s2 / Rr);
    size_t NR = (size_t)N * Rr;
    int groups = (bands + 7) / 8;
    int g2len = groups * 64;

    // --- workspace layout: small state first, then A buffers + WtX ---
    float* wsf = (float*)d_ws;
    int*   flags    = (int*)wsf;            // 16 ints
    float* sc       = wsf + 16;             // 8
    float* Mbuf     = wsf + 24;             // bands*Rr
    float* Wf       = Mbuf + bands * Rr;    // bands*Rr
    float* WM       = Wf + bands * Rr;      // 64
    float* G1       = WM + 64;              // 64
    float* G2       = G1 + 64;              // g2len
    float* cst_tau  = G2 + g2len;           // 8
    float* cst_plam = cst_tau + 8;          // 8
    size_t smallEnd = 24 + 2 * (size_t)bands * Rr + 128 + (size_t)g2len + 16;
    size_t Aoff = (smallEnd + 1023) & ~(size_t)1023;

    size_t need32 = (Aoff + 3 * NR) * sizeof(float);   // f32 A1+A2+WtX

    k_probe<<<1, 64, 0, stream>>>(X, s0, M0, s1, A0, s2, Wa, (long long)in_sizes[3],
                                  lambd, Larr, L2arr, parr, alarr, tauarr,
                                  Hp, Wp, N, K, flags);

    if (ws_size >= need32) {
        float* A1  = wsf + Aoff;
        float* A2  = A1 + NR;
        float* WtX = A2 + NR;
        run_all<float, float>(X, M0, A0, Wa, lambd, Larr, L2arr, parr, alarr, tauarr,
                              A1, A2, WtX, Mbuf, Wf, WM, G1, G2,
                              cst_tau, cst_plam, sc, flags, d_out,
                              N, bands, Rr, K, g2len, stream);
    } else {
        bf16* A1 = (bf16*)(wsf + Aoff);
        bf16* A2 = A1 + NR;
        __half* WtX = (__half*)(A2 + NR);   // NR halfs after the two bf16 planes
        run_all<bf16, __half>(X, M0, A0, Wa, lambd, Larr, L2arr, parr, alarr, tauarr,
                              A1, A2, WtX, Mbuf, Wf, WM, G1, G2,
                              cst_tau, cst_plam, sc, flags, d_out,
                              N, bands, Rr, K, g2len, stream);
    }
}

// Round 9
// 968.888 us; speedup vs baseline: 1.2020x; 1.0076x over previous
//
#include <hip/hip_runtime.h>
#include <hip/hip_bf16.h>
#include <hip/hip_fp16.h>
#include <cmath>

typedef __hip_bfloat16 bf16;

__device__ __forceinline__ float b2f(bf16 x) { return __bfloat162float(x); }
__device__ __forceinline__ float bfu(unsigned short s) {
    unsigned int t = ((unsigned int)s) << 16; float f;
    __builtin_memcpy(&f, &t, 4); return f;
}
__device__ __forceinline__ float ldf(const void* p, long long i, int f32) {
    return f32 ? ((const float*)p)[i] : b2f(((const bf16*)p)[i]);
}
__device__ __forceinline__ float ldA(const float* p, long long i) { return p[i]; }
__device__ __forceinline__ float ldA(const bf16* p, long long i)  { return b2f(p[i]); }
__device__ __forceinline__ void  stA(float* p, long long i, float v) { p[i] = v; }
__device__ __forceinline__ void  stA(bf16* p, long long i, float v)  { p[i] = __float2bfloat16(v); }

// WtX-typed helpers (f32 tier uses float, bf16 tier uses fp16 for mantissa)
__device__ __forceinline__ float ldW(const float* p, long long i) { return p[i]; }
__device__ __forceinline__ float ldW(const __half* p, long long i) { return __half2float(p[i]); }
__device__ __forceinline__ void  stW(float* p, long long i, float v) { p[i] = v; }
__device__ __forceinline__ void  stW(__half* p, long long i, float v) { p[i] = __float2half(v); }

// ---- vector helpers (callers guarantee alignment) ----
__device__ __forceinline__ void ld2(const float* p, float o[2]) {
    float2 u = *(const float2*)p; o[0]=u.x; o[1]=u.y;
}
__device__ __forceinline__ void ld2(const bf16* p, float o[2]) {
    unsigned int u = *(const unsigned int*)p;
    o[0]=bfu(u&0xffff); o[1]=bfu((unsigned short)(u>>16));
}

// X 2-px raw-load conversion: 2 VALU ops (shift keeps low bf16, mask keeps high)
__device__ __forceinline__ void xcvt2(unsigned int u, float o[2]) {
    unsigned int lo = u << 16;
    unsigned int hi = u & 0xffff0000u;
    __builtin_memcpy(&o[0], &lo, 4);
    __builtin_memcpy(&o[1], &hi, 4);
}
__device__ __forceinline__ void xcvt2(float2 u, float o[2]) { o[0] = u.x; o[1] = u.y; }

#define RR 8     // endmembers
#define G2CH 8   // chunks (of 128 px) per k_g2 wave
#define G2PX (G2CH * 128)

// flags: [0]=X f32? [1]=M0 [2]=A0 [3]=Wa [4]=lambd [5]=L [6]=L2 [7]=p
//        [8]=alpha [9]=tau [10]=H [11]=W [12]=Wa constant across k?
// sc: [0]=Lk [1]=alpha [2]=pk [3]=lmbda(prox) [4]=inv8 [5]=L2k

// ---------------------------------------------------------------------------
// Wave-parallel probe + W_a k-invariance detection (full bitwise check).
__global__ void k_probe(
    const void* X, long long nX, const void* M0, long long nM0,
    const void* A0, long long nA0, const void* Wa, long long nWa,
    const void* lamb, const void* Larr, const void* L2arr,
    const void* parr, const void* alarr, const void* tauarr,
    const void* Hp, const void* Wp, int N, int K, int* flags)
{
    int lane = threadIdx.x;           // 64 threads, 1 block
    const void* rnd[4] = {X, M0, A0, Wa};
    long long cnt[4] = {nX, nM0, nA0, nWa};
    unsigned long long mW = ~0ULL;
    for (int t = 0; t < 4; t++) {
        const bf16* pb = (const bf16*)rnd[t];
        long long stride = cnt[t] / 128; if (stride < 1) stride = 1;
        bool ok = true;
#pragma unroll
        for (int q = 0; q < 2; q++) {
            long long idx = (long long)(lane + q * 64) * stride;
            if (idx < cnt[t]) {
                float v = b2f(pb[idx]);
                ok = ok && (v > -100.f && v < 100.f);
            }
        }
        unsigned long long m = __ballot(ok);
        if (t == 3) mW = m;
        if (lane == 0) flags[t] = (m == 0xFFFFFFFFFFFFFFFFULL) ? 0 : 1;
    }
    // --- W_a constancy across the K leading blocks (bitwise, full) ---
    {
        int fWa = (mW == 0xFFFFFFFFFFFFFFFFULL) ? 0 : 1;   // 0 = bf16, 1 = f32
        long long perk = (K > 0) ? (nWa / K) : nWa;        // elements per k
        long long nu16 = fWa ? perk * 2 : perk;            // u16 units per block
        const unsigned short* wu = (const unsigned short*)Wa;
        bool ok = true;
        for (long long i = lane; i < nu16; i += 64) {
            unsigned short v0 = wu[i];
            for (int k2 = 1; k2 < K; k2++)
                ok = ok && (wu[i + (long long)k2 * nu16] == v0);
        }
        unsigned long long m = __ballot(ok);
        if (lane == 0) flags[12] = (m == 0xFFFFFFFFFFFFFFFFULL) ? 1 : 0;
    }
    if (lane != 0) return;
    const void* cst[6] = {lamb, Larr, L2arr, parr, alarr, tauarr};
    for (int t = 0; t < 6; t++) {
        const unsigned short* u = (const unsigned short*)cst[t];
        flags[4 + t] = (u[0] == u[1]) ? 0 : 1;
    }
    int dims[2];
    const void* dp[2] = {Hp, Wp};
    for (int t = 0; t < 2; t++) {
        int d = -1;
        int c = ((const int*)dp[t])[0];
        if (c >= 1 && c <= N && N % c == 0) d = c;
        if (d < 0) {
            float f = ((const float*)dp[t])[0];
            int cf = (int)(f + 0.5f);
            if (f >= 1.f && f <= (float)N && cf >= 1 && N % cf == 0) d = cf;
        }
        if (d < 0) {
            float g = b2f(((const bf16*)dp[t])[0]);
            int cg = (int)(g + 0.5f);
            if (g >= 1.f && g <= (float)N && cg >= 1 && N % cg == 0) d = cg;
        }
        if (d < 0) { d = 1; while ((long long)d * d < N) d <<= 1; }
        dims[t] = d;
    }
    if ((long long)dims[0] * dims[1] != N) dims[1] = N / dims[0];
    flags[10] = dims[0];
    flags[11] = dims[1];
}

// ---------------------------------------------------------------------------
// init (A0 transpose + M load) FUSED with the one-time WtX = W_0^T X pass.
// The two memory streams (A0 and X) overlap in one latency-bound kernel,
// and one full-N dispatch disappears. W is staged f32 into LDS from Wa's
// k=0 block (identical values to k_pre's Wf -> identical FMA sequence).
// Skips the WtX part when W varies across k (flags[12]==0).
template <typename T, typename TW>
__global__ void __launch_bounds__(256) k_initw(
    const void* __restrict__ A0, const void* __restrict__ M0,
    const void* __restrict__ X, const void* __restrict__ Wa,
    T* __restrict__ A1, float* __restrict__ Mbuf, TW* __restrict__ WtX,
    long long N, int bands, int MRtot, const int* __restrict__ flags)
{
    extern __shared__ float wsh[];   // bands*RR f32
    int tid = threadIdx.x;
    long long n = (long long)blockIdx.x * 256 + tid;
    int fA = flags[2], fM = flags[1];
    if (n < N) {
#pragma unroll
        for (int r = 0; r < RR; r++)
            stA(A1, (long long)r * N + n, ldf(A0, n * RR + r, fA));
    }
    if (n < MRtot) Mbuf[(int)n] = ldf(M0, n, fM);

    if (!flags[12]) return;          // uniform: all threads exit together
    int fW = flags[3];
    for (int i = tid; i < bands * RR; i += 256) wsh[i] = ldf(Wa, i, fW);
    __syncthreads();
    if (n >= N) return;

    int xf = flags[0];
    const bf16*  Xb = (const bf16*)X;
    const float* Xf = (const float*)X;
    float wx[RR];
#pragma unroll
    for (int r = 0; r < RR; r++) wx[r] = 0.f;
    float xq[8];
#pragma unroll
    for (int i = 0; i < 8; i++)
        xq[i] = (i < bands) ? (xf ? Xf[(long long)i * N + n]
                                  : b2f(Xb[(long long)i * N + n])) : 0.f;
    int b0 = 0;
    for (; b0 + 8 <= bands; b0 += 8) {
#pragma unroll
        for (int bi = 0; bi < 8; bi++) {
            float xc = xq[bi];
            int bn = b0 + 8 + bi;
            xq[bi] = (bn < bands) ? (xf ? Xf[(long long)bn * N + n]
                                        : b2f(Xb[(long long)bn * N + n])) : 0.f;
            const float* wrow = wsh + (b0 + bi) * RR;
#pragma unroll
            for (int r = 0; r < RR; r++) wx[r] = fmaf(wrow[r], xc, wx[r]);
        }
    }
#pragma unroll
    for (int bi = 0; bi < 8; bi++) {
        if (b0 + bi < bands) {
            float xc = xq[bi];
            const float* wrow = wsh + (b0 + bi) * RR;
#pragma unroll
            for (int r = 0; r < RR; r++) wx[r] = fmaf(wrow[r], xc, wx[r]);
        }
    }
#pragma unroll
    for (int r = 0; r < RR; r++) stW(WtX, (long long)r * N + n, wx[r]);
}

// ---------------------------------------------------------------------------
// Per-iteration setup. If do_updM: apply the PREVIOUS iteration's M update,
// then zero G1/G2, load Wf, constants, WM = Wf^T M (4-way band-parallel).
__global__ void k_pre(
    const void* __restrict__ Wa, const void* __restrict__ lambd,
    const void* __restrict__ Larr, const void* __restrict__ L2arr,
    const void* __restrict__ parr, const void* __restrict__ alarr,
    const void* __restrict__ tauarr, int k, int do_updM,
    float* __restrict__ Mbuf,
    float* __restrict__ Wf, float* __restrict__ WM,
    float* __restrict__ cst_tau, float* __restrict__ cst_plam,
    float* __restrict__ sc, float* __restrict__ G2, float* __restrict__ G1,
    int g2len, int bands, const int* __restrict__ flags)
{
    extern __shared__ float smem[];
    float* Ms  = smem;                       // bands*RR
    float* G1s = smem + bands * RR;          // 64
    float* sm2 = G1s + 64;                   // 256 scratch
    int tid = threadIdx.x;
    int fW = flags[3];
    if (do_updM) {
        float L2k = sc[5];  // iter k-1's L2
        for (int i = tid; i < bands * RR; i += blockDim.x) Ms[i] = Mbuf[i];
        for (int i = tid; i < 64; i += blockDim.x) G1s[i] = G1[i];
        __syncthreads();
        for (int i = tid; i < bands * RR; i += blockDim.x) {
            int r = i & 7;
            int b8 = i & ~7;
            float g = -G2[i];
#pragma unroll
            for (int r2 = 0; r2 < RR; r2++) g = fmaf(Ms[b8 + r2], G1s[r2 * RR + r], g);
            Mbuf[i] = fmaxf(Ms[i] - L2k * g, 0.f);
        }
        __syncthreads();
    }
    for (int i = tid; i < bands * RR; i += blockDim.x)
        Wf[i] = ldf(Wa, (long long)k * bands * RR + i, fW);
    for (int i = tid; i < g2len; i += blockDim.x) G2[i] = 0.f;
    if (tid < 64) G1[tid] = 0.f;
    if (tid == 0) {
        float Lk  = ldf(Larr,  k, flags[5]);
        float al  = ldf(alarr, k, flags[8]);
        float pk  = ldf(parr,  k, flags[7]);
        float ta  = ldf(tauarr,k, flags[9]);
        float L2k = ldf(L2arr, k, flags[6]);
        float lmb = (al != 0.f) ? 2.f * ta / al : 0.f;
        sc[0] = Lk; sc[1] = al; sc[2] = pk; sc[3] = lmb;
        sc[4] = (lmb > 1e-30f) ? 1.f / (8.f * lmb) : 0.f;
        sc[5] = L2k;
    }
    if (tid < RR) {
        float pk  = ldf(parr, k, flags[7]);
        float lam = ldf(lambd, (long long)k * RR + tid, flags[4]);
        float e1 = 1.f / (2.f - pk);
        float e2 = (pk - 1.f) / (2.f - pk);
        float t = powf(2.f * (1.f - pk) * lam, e1)
                + pk * lam * powf(2.f * lam * (1.f - pk), e2);
        cst_tau[tid]  = t;
        cst_plam[tid] = pk * lam;
    }
    __syncthreads();
    {
        int pr = tid >> 2, qt = tid & 3;     // tid < 256
        int r = pr >> 3, r2 = pr & 7;
        float s = 0.f;
        for (int b = qt; b < bands; b += 4) s += Wf[b * RR + r] * Mbuf[b * RR + r2];
        sm2[tid] = s;
    }
    __syncthreads();
    if (tid < RR * RR)
        WM[tid] = sm2[tid * 4] + sm2[tid * 4 + 1] + sm2[tid * 4 + 2] + sm2[tid * 4 + 3];
}

// ---------------------------------------------------------------------------
// update_A. W-constant fast path: wx streamed from precomputed WtX (no X
// read). Fallback (W varies per k): on-the-fly band loop with 8-deep ring.
// Wave-uniform branch on flags[12].
template <typename T, typename TW>
__global__ void __launch_bounds__(256) k_updA(
    const void* __restrict__ X, const T* __restrict__ A1,
    const TW* __restrict__ WtX,
    const float* __restrict__ Wf, const float* __restrict__ WM,
    const float* __restrict__ cst_tau, const float* __restrict__ cst_plam,
    const float* __restrict__ sc, T* __restrict__ A2,
    long long N, int bands, const int* __restrict__ flags, int first)
{
    long long n = (long long)blockIdx.x * 256 + threadIdx.x;
    if (n >= N) return;

    float wx[RR];
    if (flags[12]) {
#pragma unroll
        for (int r = 0; r < RR; r++) wx[r] = ldW(WtX, (long long)r * N + n);
    } else {
        int xf = flags[0];
        const bf16*  Xb = (const bf16*)X;
        const float* Xf = (const float*)X;
#pragma unroll
        for (int r = 0; r < RR; r++) wx[r] = 0.f;
        float xq[8];
#pragma unroll
        for (int i = 0; i < 8; i++)
            xq[i] = (i < bands) ? (xf ? Xf[(long long)i * N + n]
                                      : b2f(Xb[(long long)i * N + n])) : 0.f;
        int b0 = 0;
        for (; b0 + 8 <= bands; b0 += 8) {
#pragma unroll
            for (int bi = 0; bi < 8; bi++) {
                float xc = xq[bi];
                int bn = b0 + 8 + bi;
                xq[bi] = (bn < bands) ? (xf ? Xf[(long long)bn * N + n]
                                            : b2f(Xb[(long long)bn * N + n])) : 0.f;
                const float* wrow = Wf + (b0 + bi) * RR;
#pragma unroll
                for (int r = 0; r < RR; r++) wx[r] = fmaf(wrow[r], xc, wx[r]);
            }
        }
#pragma unroll
        for (int bi = 0; bi < 8; bi++) {
            if (b0 + bi < bands) {
                float xc = xq[bi];
                const float* wrow = Wf + (b0 + bi) * RR;
#pragma unroll
                for (int r = 0; r < RR; r++) wx[r] = fmaf(wrow[r], xc, wx[r]);
            }
        }
    }

    float a[RR], bv[RR];
#pragma unroll
    for (int r = 0; r < RR; r++) a[r] = ldA(A1, (long long)r * N + n);
    if (first) {
#pragma unroll
        for (int r = 0; r < RR; r++) bv[r] = a[r];
    } else {
        float sb = 0.f;
#pragma unroll
        for (int r = 0; r < RR; r++) { float rl = fmaxf(a[r], 0.f); bv[r] = rl; sb += rl; }
        float invb = 1.f / (sb + 1e-4f);
#pragma unroll
        for (int r = 0; r < RR; r++) bv[r] *= invb;
    }

    // ---- prox-gradient step ----
    float Lk = sc[0], al = sc[1], pk = sc[2];
    float o[RR]; float s = 0.f;
#pragma unroll
    for (int r = 0; r < RR; r++) {
        float gg = al * (a[r] - bv[r]) - wx[r];
#pragma unroll
        for (int r2 = 0; r2 < RR; r2++) gg = fmaf(WM[r * RR + r2], a[r2], gg);
        float v = a[r] - Lk * gg;
        float t = 0.f;
        if (v > cst_tau[r]) {
            float vp = (pk == 0.5f) ? rsqrtf(v) : powf(v, pk - 1.f);
            t = v - cst_plam[r] * vp;
        }
        t = fminf(t, 1.f);
        t = fmaxf(t, 0.f);
        o[r] = t;
        s += t;
    }
    float inv = 1.f / (s + 1e-4f);
#pragma unroll
    for (int r = 0; r < RR; r++) stA(A2, (long long)r * N + n, o[r] * inv);
}

// ---------------------------------------------------------------------------
// prox_TV per pixel per channel (unchanged).
template <typename T>
__global__ void __launch_bounds__(256) k_prox(
    const T* __restrict__ Ain, T* __restrict__ Aout,
    const float* __restrict__ sc, const int* __restrict__ flags, int N)
{
    int n = blockIdx.x * blockDim.x + threadIdx.x;
    if (n >= N) return;
    int H = flags[10], W = flags[11];
    int i = n / W, j = n % W;
    float lmb  = sc[3];
    float inv8 = sc[4];
#pragma unroll
    for (int r = 0; r < RR; r++) {
        const T* img = Ain + (long long)r * N;
        float c   = ldA(img, n);
        float dwn = (i < H - 1) ? ldA(img, n + W) : c;
        float rgt = (j < W - 1) ? ldA(img, n + 1) : c;
        float rr0 = (c - dwn) * inv8;
        float ss0 = (c - rgt) * inv8;
        float w0 = fmaxf(1.f, sqrtf(rr0 * rr0 + ss0 * ss0 + 1e-8f));
        float rn00 = rr0 / w0, sn00 = ss0 / w0;
        float rnU = 0.f;
        if (i > 0) {
            float cu = ldA(img, n - W);
            float ru = (j < W - 1) ? ldA(img, n - W + 1) : cu;
            float rru = (cu - c) * inv8;
            float ssu = (cu - ru) * inv8;
            float wu = fmaxf(1.f, sqrtf(rru * rru + ssu * ssu + 1e-8f));
            rnU = rru / wu;
        }
        float snL = 0.f;
        if (j > 0) {
            float cl = ldA(img, n - 1);
            float dl = (i < H - 1) ? ldA(img, n + W - 1) : cl;
            float rrl = (cl - dl) * inv8;
            float ssl = (cl - c) * inv8;
            float wl2 = fmaxf(1.f, sqrtf(rrl * rrl + ssl * ssl + 1e-8f));
            snL = ssl / wl2;
        }
        float div = rn00 - rnU + sn00 - snL;
        stA(Aout, (long long)r * N + n, c - lmb * div);
    }
}

// ---------------------------------------------------------------------------
// Butterfly stages with compile-time indexing (round-2 lesson).
template <int H>
__device__ __forceinline__ void bstep(float* v, int lane) {
    int up = (lane & H) != 0;
#pragma unroll
    for (int i = 0; i < H; i++) {
        float give = up ? v[i] : v[i + H];
        float keep = up ? v[i + H] : v[i];
        v[i] = keep + __shfl_xor(give, H, 64);
    }
}
// 32 columns over 64 lanes: after the xor-32 fold, lanes l and l+32 both
// hold column (l&31); bstep<16..1> finishes. Caller uses lanes < 32.
__device__ __forceinline__ float butterfly32(float v[32], int lane) {
#pragma unroll
    for (int i = 0; i < 32; i++) v[i] += __shfl_xor(v[i], 32, 64);
    bstep<16>(v, lane);
    bstep<8>(v, lane);
    bstep<4>(v, lane);
    bstep<2>(v, lane);
    bstep<1>(v, lane);
    return v[0];
}

// ---------------------------------------------------------------------------
// G2 = X A^T and G1 = A A^T, split by (4-band group, pixel-tile).
// pacc[32] targets <=64 VGPR = the 8-waves/SIMD occupancy step (m69);
// round-7 validated this kernel's correctness; this round isolates its
// performance (round 7 bundled it with an updA change that regressed).
// grid = (ceil(N/1024), ngroups4 + 2); last two slots do G1 rows 0-3/4-7.
template <typename T>
__global__ void __launch_bounds__(64) k_g2(
    const void* __restrict__ X, const T* __restrict__ A,
    float* __restrict__ G2, float* __restrict__ G1,
    long long N, int bands, int ngroups4, const int* __restrict__ flags)
{
    int lane = threadIdx.x;
    long long p0 = (long long)blockIdx.x * G2PX;
    int gy = blockIdx.y;
    int xf = flags[0];
    int fast = (p0 + G2PX <= N) && ((N & 1LL) == 0);

    float pacc[32];
#pragma unroll
    for (int q = 0; q < 32; q++) pacc[q] = 0.f;

    if (gy < ngroups4) {
        int b0 = gy * 4;
        if (fast) {
            long long half = N >> 1;
#pragma unroll
            for (int c = 0; c < G2CH; c++) {
                long long base = p0 + (long long)c * 128 + lane * 2;
                long long gi = base >> 1;
                float xv[4][2];
                if (!xf) {
                    const unsigned int* Xu = (const unsigned int*)X;
#pragma unroll
                    for (int bi = 0; bi < 4; bi++) {
                        int b = b0 + bi;
                        unsigned int u = (b < bands) ? Xu[(long long)b * half + gi] : 0u;
                        xcvt2(u, xv[bi]);
                    }
                } else {
                    const float2* Xf2 = (const float2*)X;
#pragma unroll
                    for (int bi = 0; bi < 4; bi++) {
                        int b = b0 + bi;
                        float2 u = (b < bands) ? Xf2[(long long)b * half + gi]
                                               : make_float2(0.f, 0.f);
                        xcvt2(u, xv[bi]);
                    }
                }
#pragma unroll
                for (int r = 0; r < RR; r++) {
                    float av[2];
                    ld2(A + (long long)r * N + base, av);
#pragma unroll
                    for (int bi = 0; bi < 4; bi++)
                        pacc[bi * 8 + r] = fmaf(xv[bi][0], av[0],
                                            fmaf(xv[bi][1], av[1], pacc[bi * 8 + r]));
                }
            }
        } else {
            for (int c = 0; c < G2CH; c++) {
                long long n0 = p0 + (long long)c * 128;
                if (n0 >= N) break;
                long long base = n0 + lane * 2;
                float xv[4][2] = {};
#pragma unroll
                for (int bi = 0; bi < 4; bi++) {
                    int b = b0 + bi;
#pragma unroll
                    for (int t = 0; t < 2; t++) {
                        long long idx = base + t;
                        if (b < bands && idx < N)
                            xv[bi][t] = ldf(X, (long long)b * N + idx, xf);
                    }
                }
#pragma unroll
                for (int r = 0; r < RR; r++) {
                    float av[2] = {0.f, 0.f};
#pragma unroll
                    for (int t = 0; t < 2; t++) {
                        long long idx = base + t;
                        if (idx < N) av[t] = ldA(A, (long long)r * N + idx);
                    }
#pragma unroll
                    for (int bi = 0; bi < 4; bi++)
                        pacc[bi * 8 + r] = fmaf(xv[bi][0], av[0],
                                            fmaf(xv[bi][1], av[1], pacc[bi * 8 + r]));
                }
            }
        }
        float s = butterfly32(pacc, lane);
        int q = lane & 31;
        int b = b0 + (q >> 3);
        if (lane < 32 && b < bands) atomicAdd(&G2[b * 8 + (q & 7)], s);
    } else {
        // G1 rows r0..r0+3 (r0 = 0 or 4)
        int r0 = (gy - ngroups4) * 4;
        if (fast) {
#pragma unroll
            for (int c = 0; c < G2CH; c++) {
                long long base = p0 + (long long)c * 128 + lane * 2;
                float xv[4][2];
#pragma unroll
                for (int bi = 0; bi < 4; bi++) ld2(A + (long long)(r0 + bi) * N + base, xv[bi]);
#pragma unroll
                for (int r = 0; r < RR; r++) {
                    float av[2];
                    ld2(A + (long long)r * N + base, av);
#pragma unroll
                    for (int bi = 0; bi < 4; bi++)
                        pacc[bi * 8 + r] = fmaf(xv[bi][0], av[0],
                                            fmaf(xv[bi][1], av[1], pacc[bi * 8 + r]));
                }
            }
        } else {
            for (int c = 0; c < G2CH; c++) {
                long long n0 = p0 + (long long)c * 128;
                if (n0 >= N) break;
                long long base = n0 + lane * 2;
                float xv[4][2] = {};
#pragma unroll
                for (int bi = 0; bi < 4; bi++)
#pragma unroll
                    for (int t = 0; t < 2; t++) {
                        long long idx = base + t;
                        if (idx < N) xv[bi][t] = ldA(A, (long long)(r0 + bi) * N + idx);
                    }
#pragma unroll
                for (int r = 0; r < RR; r++) {
                    float av[2] = {0.f, 0.f};
#pragma unroll
                    for (int t = 0; t < 2; t++) {
                        long long idx = base + t;
                        if (idx < N) av[t] = ldA(A, (long long)r * N + idx);
                    }
#pragma unroll
                    for (int bi = 0; bi < 4; bi++)
                        pacc[bi * 8 + r] = fmaf(xv[bi][0], av[0],
                                            fmaf(xv[bi][1], av[1], pacc[bi * 8 + r]));
                }
            }
        }
        float s = butterfly32(pacc, lane);
        int q = lane & 31;
        if (lane < 32) atomicAdd(&G1[(r0 + (q >> 3)) * 8 + (q & 7)], s);
    }
}

// ---------------------------------------------------------------------------
// Final M update (last iteration only; earlier ones are folded into k_pre).
__global__ void __launch_bounds__(256) k_updateM(
    float* __restrict__ Mbuf, const float* __restrict__ G1,
    const float* __restrict__ G2, const float* __restrict__ sc, int bands)
{
    extern __shared__ float smem[];
    float* Ms  = smem;
    float* G1s = smem + bands * RR;
    int tid = threadIdx.x;
    for (int i = tid; i < bands * RR; i += 256) Ms[i] = Mbuf[i];
    for (int i = tid; i < RR * RR; i += 256) G1s[i] = G1[i];
    __syncthreads();
    float L2k = sc[5];
    for (int i = tid; i < bands * RR; i += 256) {
        int b = i >> 3, r = i & 7;
        float g = -G2[i];
#pragma unroll
        for (int r2 = 0; r2 < RR; r2++) g = fmaf(Ms[b * RR + r2], G1s[r2 * RR + r], g);
        Mbuf[i] = fmaxf(Ms[i] - L2k * g, 0.f);
    }
}

// ---------------------------------------------------------------------------
template <typename T>
__global__ void __launch_bounds__(256) k_out(
    const float* __restrict__ Mbuf, const T* __restrict__ A1,
    void* __restrict__ out, int MR, int RN, const int* __restrict__ flags)
{
    int i = blockIdx.x * blockDim.x + threadIdx.x;
    if (flags[0]) {
        float* o = (float*)out;
        if (i < MR) o[i] = Mbuf[i];
        if (i < RN) o[MR + i] = ldA(A1, i);
    } else {
        bf16* o = (bf16*)out;
        if (i < MR) o[i] = __float2bfloat16(Mbuf[i]);
        if (i < RN) o[MR + i] = __float2bfloat16(ldA(A1, i));
    }
}

// ---------------------------------------------------------------------------
template <typename T, typename TW>
static void run_all(const void* X, const void* M0, const void* A0, const void* Wa,
                    const void* lambd, const void* Larr, const void* L2arr,
                    const void* parr, const void* alarr, const void* tauarr,
                    T* A1, T* A2, TW* WtX, float* Mbuf, float* Wf,
                    float* WM, float* G1, float* G2, float* cst_tau, float* cst_plam,
                    float* sc, int* flags, void* out,
                    int N, int bands, int Rr, int K, int g2len, hipStream_t stream)
{
    int nb = (N + 255) / 256;
    int ntiles = (N + G2PX - 1) / G2PX;
    int ngroups4 = (bands + 3) / 4;
    int MR = bands * Rr;
    size_t smem_pre  = ((size_t)bands * Rr + 64 + 256) * sizeof(float);
    size_t smem_init = (size_t)bands * Rr * sizeof(float);

    // fused init + one-time WtX (self-disables WtX part if W varies per k)
    k_initw<T, TW><<<nb, 256, smem_init, stream>>>(A0, M0, X, Wa, A1, Mbuf, WtX,
                                                   (long long)N, bands, MR, flags);

    for (int k = 0; k < K; k++) {
        k_pre<<<1, 256, smem_pre, stream>>>(Wa, lambd, Larr, L2arr, parr, alarr,
                                            tauarr, k, (k > 0) ? 1 : 0, Mbuf, Wf, WM,
                                            cst_tau, cst_plam, sc, G2, G1,
                                            g2len, bands, flags);
        k_updA<T, TW><<<nb, 256, 0, stream>>>(X, A1, WtX, Wf, WM, cst_tau, cst_plam,
                                              sc, A2, (long long)N, bands, flags,
                                              (k == 0) ? 1 : 0);
        k_prox<T><<<nb, 256, 0, stream>>>(A2, A1, sc, flags, N);
        k_g2<T><<<dim3(ntiles, ngroups4 + 2), 64, 0, stream>>>(X, A1, G2, G1,
                                                               (long long)N, bands,
                                                               ngroups4, flags);
    }
    k_updateM<<<1, 256, smem_pre, stream>>>(Mbuf, G1, G2, sc, bands);
    k_out<T><<<((size_t)N * Rr + 255) / 256, 256, 0, stream>>>(Mbuf, A1, out, MR, N * Rr, flags);
}

// ---------------------------------------------------------------------------
extern "C" void kernel_launch(void* const* d_in, const int* in_sizes, int n_in,
                              void* d_out, int out_size, void* d_ws, size_t ws_size,
                              hipStream_t stream)
{
    const void* X      = d_in[0];
    const void* M0     = d_in[1];
    const void* A0     = d_in[2];
    const void* Wa     = d_in[3];
    const void* lambd  = d_in[4];
    const void* Larr   = d_in[5];
    const void* L2arr  = d_in[6];
    const void* parr   = d_in[7];
    const void* alarr  = d_in[8];
    const void* tauarr = d_in[9];
    const void* Hp     = d_in[10];
    const void* Wp     = d_in[11];

    int K = in_sizes[5];
    long long s0 = in_sizes[0], s1 = in_sizes[1], s2 = in_sizes[2];
    int Rr = (int)llround(sqrt((double)(s1 * s2) / (double)s0));  // == 8
    int bands = (int)(s1 / Rr);
    int N = (int)(s2 / Rr);
    size_t NR = (size_t)N * Rr;
    int g2len = bands * Rr;

    // --- workspace layout: small state first, then A buffers + WtX ---
    float* wsf = (float*)d_ws;
    int*   flags    = (int*)wsf;            // 16 ints
    float* sc       = wsf + 16;             // 8
    float* Mbuf     = wsf + 24;             // bands*Rr
    float* Wf       = Mbuf + bands * Rr;    // bands*Rr
    float* WM       = Wf + bands * Rr;      // 64
    float* G1       = WM + 64;              // 64
    float* G2       = G1 + 64;              // g2len
    float* cst_tau  = G2 + g2len;           // 8
    float* cst_plam = cst_tau + 8;          // 8
    size_t smallEnd = 24 + 2 * (size_t)bands * Rr + 128 + (size_t)g2len + 16;
    size_t Aoff = (smallEnd + 1023) & ~(size_t)1023;

    size_t need32 = (Aoff + 3 * NR) * sizeof(float);   // f32 A1+A2+WtX

    k_probe<<<1, 64, 0, stream>>>(X, s0, M0, s1, A0, s2, Wa, (long long)in_sizes[3],
                                  lambd, Larr, L2arr, parr, alarr, tauarr,
                                  Hp, Wp, N, K, flags);

    if (ws_size >= need32) {
        float* A1  = wsf + Aoff;
        float* A2  = A1 + NR;
        float* WtX = A2 + NR;
        run_all<float, float>(X, M0, A0, Wa, lambd, Larr, L2arr, parr, alarr, tauarr,
                              A1, A2, WtX, Mbuf, Wf, WM, G1, G2,
                              cst_tau, cst_plam, sc, flags, d_out,
                              N, bands, Rr, K, g2len, stream);
    } else {
        bf16* A1 = (bf16*)(wsf + Aoff);
        bf16* A2 = A1 + NR;
        __half* WtX = (__half*)(A2 + NR);   // NR halfs after the two bf16 planes
        run_all<bf16, __half>(X, M0, A0, Wa, lambd, Larr, L2arr, parr, alarr, tauarr,
                              A1, A2, WtX, Mbuf, Wf, WM, G1, G2,
                              cst_tau, cst_plam, sc, flags, d_out,
                              N, bands, Rr, K, g2len, stream);
    }
}